// Round 13
// baseline (154.565 us; speedup 1.0000x reference)
//
#include <hip/hip_runtime.h>
#include <hip/hip_bf16.h>

#define BB 16
#define EE 128
#define MM 64
#define DQ 768
#define DK 256

typedef __attribute__((ext_vector_type(8))) short short8v;    // 8 bf16 = 4 VGPR
typedef __attribute__((ext_vector_type(4))) float f32x4;

#define MFMA16(a, b, c) __builtin_amdgcn_mfma_f32_16x16x32_bf16(a, b, c, 0, 0, 0)

// raw barrier: LDS visibility only; leaves global loads/stores in flight
#define LDS_BARRIER() asm volatile("s_waitcnt lgkmcnt(0)\n\ts_barrier" ::: "memory")

__device__ __forceinline__ ushort f2bf(float f) {
  __hip_bfloat16 h = __float2bfloat16(f);
  return *reinterpret_cast<ushort*>(&h);
}
__device__ __forceinline__ uint pack2(float lo, float hi) {
  return (uint)f2bf(lo) | ((uint)f2bf(hi) << 16);
}

// ---------------------------------------------------------------------------
// K1: WfT[e][d] = sum_k Wq[d][k] * Wk[e][k]  (= (Wq @ Wk^T)^T, bf16) via MFMA.
// ---------------------------------------------------------------------------
__global__ __launch_bounds__(64) void k_wfuse(const float* __restrict__ Wq,
                                              const float* __restrict__ Wk,
                                              ushort* __restrict__ wfT) {
  const int lane = threadIdx.x & 63;
  const int lo = lane & 15, hi = lane >> 4;
  const int e0 = blockIdx.x * 16;
  const int d0 = blockIdx.y * 64;
  f32x4 acc[4] = {f32x4{0.f, 0.f, 0.f, 0.f}, f32x4{0.f, 0.f, 0.f, 0.f},
                  f32x4{0.f, 0.f, 0.f, 0.f}, f32x4{0.f, 0.f, 0.f, 0.f}};
#pragma unroll
  for (int ks = 0; ks < 8; ++ks) {
    const int k = ks * 32 + 8 * hi;
    const float4 a0 = *(const float4*)&Wk[(size_t)(e0 + lo) * DK + k];
    const float4 a1 = *(const float4*)&Wk[(size_t)(e0 + lo) * DK + k + 4];
    union { short8v v; uint u[4]; } av;
    av.u[0] = pack2(a0.x, a0.y); av.u[1] = pack2(a0.z, a0.w);
    av.u[2] = pack2(a1.x, a1.y); av.u[3] = pack2(a1.z, a1.w);
#pragma unroll
    for (int dt = 0; dt < 4; ++dt) {
      const float4 b0 = *(const float4*)&Wq[(size_t)(d0 + dt * 16 + lo) * DK + k];
      const float4 b1 = *(const float4*)&Wq[(size_t)(d0 + dt * 16 + lo) * DK + k + 4];
      union { short8v v; uint u[4]; } bv;
      bv.u[0] = pack2(b0.x, b0.y); bv.u[1] = pack2(b0.z, b0.w);
      bv.u[2] = pack2(b1.x, b1.y); bv.u[3] = pack2(b1.z, b1.w);
      acc[dt] = MFMA16(av.v, bv.v, acc[dt]);
    }
  }
#pragma unroll
  for (int dt = 0; dt < 4; ++dt)
#pragma unroll
    for (int r = 0; r < 4; ++r)
      wfT[(size_t)(e0 + 4 * hi + r) * DQ + d0 + dt * 16 + lo] = f2bf(acc[dt][r]);
}

// ---------------------------------------------------------------------------
// K2: qt2[r][e] = (sum_d relu(querys[r][d]) * WfT[e][d]) * scale + Wm_w[e].
// Scale + mention-bias weight folded into the query side (f32 fold, bf16 out).
// ---------------------------------------------------------------------------
__global__ __launch_bounds__(128) void k_qt(const float* __restrict__ querys,
                                            const ushort* __restrict__ wfT,
                                            const float* __restrict__ wm_w,
                                            ushort* __restrict__ qt) {
  const int tid = threadIdx.x;
  const int w = tid >> 6;
  const int lane = tid & 63;
  const int lo = lane & 15, hi = lane >> 4;
  const int r0 = blockIdx.x * 32 + w * 16;
  const int e0 = blockIdx.y * 64;
  const float* qrow = querys + (size_t)(r0 + lo) * DQ;
  f32x4 acc[4] = {f32x4{0.f, 0.f, 0.f, 0.f}, f32x4{0.f, 0.f, 0.f, 0.f},
                  f32x4{0.f, 0.f, 0.f, 0.f}, f32x4{0.f, 0.f, 0.f, 0.f}};
#pragma unroll
  for (int kc = 0; kc < DQ; kc += 32) {
    const int k = kc + 8 * hi;
    const float4 a0 = *(const float4*)&qrow[k];
    const float4 a1 = *(const float4*)&qrow[k + 4];
    union { short8v v; uint u[4]; } af;
    af.u[0] = pack2(fmaxf(a0.x, 0.f), fmaxf(a0.y, 0.f));
    af.u[1] = pack2(fmaxf(a0.z, 0.f), fmaxf(a0.w, 0.f));
    af.u[2] = pack2(fmaxf(a1.x, 0.f), fmaxf(a1.y, 0.f));
    af.u[3] = pack2(fmaxf(a1.z, 0.f), fmaxf(a1.w, 0.f));
#pragma unroll
    for (int et = 0; et < 4; ++et) {
      const short8v bf = *(const short8v*)&wfT[(size_t)(e0 + et * 16 + lo) * DQ + k];
      acc[et] = MFMA16(af.v, bf, acc[et]);
    }
  }
  const float sc = 0.036084391824351615f;  // 1/sqrt(768)
#pragma unroll
  for (int et = 0; et < 4; ++et) {
    const float wmv = wm_w[e0 + et * 16 + lo];
#pragma unroll
    for (int r = 0; r < 4; ++r)
      qt[(size_t)(r0 + hi * 4 + r) * DK + e0 + et * 16 + lo] =
          f2bf(fmaf(acc[et][r], sc, wmv));
  }
}

// ---------------------------------------------------------------------------
// K3: fused MFMA attention, SINGLE-barrier free-running edition.
// 512 thr = 8 waves, one (b,a) per block, grid 2048, 2 blocks/CU.
// LDS = raw keys 32K (QK source; relu applied in-register via i16 max) +
//       kT 32K (PV source, row-readable) = 64 KiB. NO P_lds: P stays in
// registers (r5/r6 shuffle redistribute). After BAR1 every wave free-runs
// QK -> softmax -> P redistribute -> PV -> stores: no block-wide phase lock,
// so the 16 resident waves/CU stagger their HBM load/store bursts.
// ---------------------------------------------------------------------------
__global__ __launch_bounds__(512, 4) void k_attn(
    const float* __restrict__ keys, const ushort* __restrict__ qt,
    const int* __restrict__ masks, float* __restrict__ out) {
  __shared__ ushort key_lds[MM * DK];    // 32 KiB raw bf16, swz ((m&7)^(((m>>3)&1)<<2))<<4
  __shared__ ushort kT_lds[DK * MM];     // 32 KiB kT bf16,  swz ((d&7)^((d>>3)&7))<<4

  const int tid = threadIdx.x;
  const int w = tid >> 6;
  const int lane = tid & 63;
  const int lo = lane & 15, hi = lane >> 4;
  const int ba = blockIdx.x;             // b*EE + a
  const int b = ba >> 7;

  // ================= stage: keys -> key_lds (raw) + kT_lds (transposed) ====
  // 16-lane group hi of wave w owns row pair (m0, m0+1); lane lo covers
  // f32x4 chunks c = lo + 16*it.
  {
    const int m0 = w * 8 + hi * 2;
    const int sw0 = ((m0 & 7) ^ (((m0 >> 3) & 1) << 2)) << 4;
    const int sw1 = (((m0 + 1) & 7) ^ ((((m0 + 1) >> 3) & 1) << 2)) << 4;
    const float4* kb4 = (const float4*)(keys + (size_t)ba * (MM * DK));
#pragma unroll
    for (int it = 0; it < 4; ++it) {
      const int c = lo + 16 * it;
      const float4 va = kb4[(size_t)m0 * 64 + c];
      const float4 vb = kb4[(size_t)(m0 + 1) * 64 + c];
      uint2 ra, rb;
      ra.x = pack2(va.x, va.y); ra.y = pack2(va.z, va.w);
      rb.x = pack2(vb.x, vb.y); rb.y = pack2(vb.z, vb.w);
      *(uint2*)((char*)key_lds + (size_t)m0 * 512 + ((8 * c) ^ sw0)) = ra;
      *(uint2*)((char*)key_lds + (size_t)(m0 + 1) * 512 + ((8 * c) ^ sw1)) = rb;
      const float va4[4] = {va.x, va.y, va.z, va.w};
      const float vb4[4] = {vb.x, vb.y, vb.z, vb.w};
#pragma unroll
      for (int j = 0; j < 4; ++j) {
        const int d = 4 * c + j;
        const int sw = ((d & 7) ^ ((d >> 3) & 7)) << 4;
        *(uint*)((char*)kT_lds + (size_t)d * 128 + ((2 * m0) ^ sw)) =
            pack2(va4[j], vb4[j]);
      }
    }
  }

  // qt2 B-fragments for QK (cols q = w*16+lo); issued while barrier drains
  const ushort* qrowp = qt + ((size_t)b * EE + w * 16 + lo) * DK + 8 * hi;
  short8v aq[8];
#pragma unroll
  for (int ks = 0; ks < 8; ++ks) aq[ks] = *(const short8v*)(qrowp + 32 * ks);

  LDS_BARRIER();   // the ONLY barrier: staging visible; waves free-run after

  // ====== QK^T swapped 16x16: full logits S^T[m][q], lane q = w*16+lo ======
  // A-operand = relu(keys) applied in-register via packed i16 max.
  const short8v zero8 = {0, 0, 0, 0, 0, 0, 0, 0};
  const int swm = ((lo & 7) ^ (((lo >> 3) & 1) << 2)) << 4;  // sw(m=mt*16+lo)
  f32x4 sacc[4] = {f32x4{0.f, 0.f, 0.f, 0.f}, f32x4{0.f, 0.f, 0.f, 0.f},
                   f32x4{0.f, 0.f, 0.f, 0.f}, f32x4{0.f, 0.f, 0.f, 0.f}};
  __builtin_amdgcn_s_setprio(1);
#pragma unroll
  for (int ks = 0; ks < 8; ++ks) {
#pragma unroll
    for (int mt = 0; mt < 4; ++mt) {
      const int m = mt * 16 + lo;
      short8v bf = *(const short8v*)((char*)key_lds + (size_t)m * 512 +
                                     ((((ks * 4 + hi) << 4)) ^ swm));
      bf = __builtin_elementwise_max(bf, zero8);   // bf16 relu (i16 max vs 0)
      sacc[mt] = MFMA16(bf, aq[ks], sacc[mt]);     // A = relu_k, B = qt2
    }
  }
  __builtin_amdgcn_s_setprio(0);

  // mask bits for this lane's softmax rows: m = mt*16 + hi*4 .. +3
  const int4* mrow = (const int4*)(masks + (size_t)ba * MM);
  int4 mk4[4];
#pragma unroll
  for (int mt = 0; mt < 4; ++mt) mk4[mt] = mrow[mt * 4 + hi];

  // ============ softmax: mask select, in-lane 16 m + shfl_xor 16,32 ========
  float l[4][4];
  float mx = -3.4e38f;
#pragma unroll
  for (int mt = 0; mt < 4; ++mt) {
    const int mkb[4] = {mk4[mt].x, mk4[mt].y, mk4[mt].z, mk4[mt].w};
#pragma unroll
    for (int r = 0; r < 4; ++r) {
      l[mt][r] = (mkb[r] != 0) ? sacc[mt][r] : -1e30f;
      mx = fmaxf(mx, l[mt][r]);
    }
  }
  mx = fmaxf(mx, __shfl_xor(mx, 16));
  mx = fmaxf(mx, __shfl_xor(mx, 32));
  float s = 0.f;
#pragma unroll
  for (int mt = 0; mt < 4; ++mt)
#pragma unroll
    for (int r = 0; r < 4; ++r) {
      l[mt][r] = __expf(l[mt][r] - mx);
      s += l[mt][r];
    }
  s += __shfl_xor(s, 16);
  s += __shfl_xor(s, 32);
  const float rinv = 1.f / s;

  // pack P column (q = w*16+lo) to bf16 pairs
  uint pk0[4], pk1[4];
#pragma unroll
  for (int mt = 0; mt < 4; ++mt) {
    pk0[mt] = pack2(l[mt][0] * rinv, l[mt][1] * rinv);
    pk1[mt] = pack2(l[mt][2] * rinv, l[mt][3] * rinv);
  }

  // ======== redistribute P into PV B-fragment layout (16 shuffles) =========
  // (r5/r6 verified code) target lane (lo,hi) frag[ks] holds P[m][q=w*16+lo],
  // m = ks*32 + 8*hi + 0..7.
  const int srcA = lo + 32 * ((lane >> 4) & 1);
  const int srcB = srcA + 16;
  uint sa0[4], sa1[4], sb0[4], sb1[4];
#pragma unroll
  for (int mt = 0; mt < 4; ++mt) {
    sa0[mt] = (uint)__shfl((int)pk0[mt], srcA);
    sa1[mt] = (uint)__shfl((int)pk1[mt], srcA);
    sb0[mt] = (uint)__shfl((int)pk0[mt], srcB);
    sb1[mt] = (uint)__shfl((int)pk1[mt], srcB);
  }
  const bool ms = (hi >> 1) & 1;
  union { short8v v; uint u[4]; } pf0, pf1;
  pf0.u[0] = ms ? sa0[1] : sa0[0];
  pf0.u[1] = ms ? sa1[1] : sa1[0];
  pf0.u[2] = ms ? sb0[1] : sb0[0];
  pf0.u[3] = ms ? sb1[1] : sb1[0];
  pf1.u[0] = ms ? sa0[3] : sa0[2];
  pf1.u[1] = ms ? sa1[3] : sa1[2];
  pf1.u[2] = ms ? sb0[3] : sb0[2];
  pf1.u[3] = ms ? sb1[3] : sb1[2];

  // ================= PV: swapped D[d][q], wave owns q = w*16..+15, 256 d ===
  // (r5/r6 verified) A = kT rows d (conflict-free b128), B = P (cols q).
  float* ob = out + ((size_t)ba * EE + w * 16 + lo) * DK;  // this lane's q row
  __builtin_amdgcn_s_setprio(1);
#pragma unroll
  for (int dt = 0; dt < 16; ++dt) {
    const int d = dt * 16 + lo;
    const int sw = ((d & 7) ^ ((d >> 3) & 7)) << 4;
    const short8v bk0 = *(const short8v*)((char*)kT_lds + (size_t)d * 128 +
                                          ((16 * hi) ^ sw));
    const short8v bk1 = *(const short8v*)((char*)kT_lds + (size_t)d * 128 +
                                          ((64 + 16 * hi) ^ sw));
    f32x4 o = {0.f, 0.f, 0.f, 0.f};
    o = MFMA16(bk0, pf0.v, o);   // A = kT (rows d, k=m), B = P (cols q)
    o = MFMA16(bk1, pf1.v, o);
    float4 ov;
    ov.x = o[0]; ov.y = o[1]; ov.z = o[2]; ov.w = o[3];
    *(float4*)&ob[dt * 16 + hi * 4] = ov;   // 4 consecutive d, one q
  }
  __builtin_amdgcn_s_setprio(0);
}

// ---------------------------------------------------------------------------
extern "C" void kernel_launch(void* const* d_in, const int* in_sizes, int n_in,
                              void* d_out, int out_size, void* d_ws, size_t ws_size,
                              hipStream_t stream) {
  const float* querys = (const float*)d_in[0];  // [16,128,768]
  const float* keys   = (const float*)d_in[1];  // [16,128,64,256]
  const float* Wq     = (const float*)d_in[2];  // [768,256]
  const float* Wk     = (const float*)d_in[3];  // [256,256]
  const float* Wm_w   = (const float*)d_in[4];  // [256]
  // d_in[5] = Wm_b: row-constant logit shift -> cancels in softmax; unused.
  const int*   masks  = (const int*)d_in[6];    // [16,128,64]
  float* out = (float*)d_out;                   // [16,128,128,256]

  ushort* wfT   = (ushort*)d_ws;                          // 256*768 bf16
  ushort* qt_bf = (ushort*)((char*)d_ws + DK * DQ * 2);   // 2048*256 bf16

  k_wfuse<<<dim3(DK / 16, DQ / 64), 64, 0, stream>>>(Wq, Wk, wfT);
  k_qt<<<dim3((BB * EE) / 32, DK / 64), 128, 0, stream>>>(querys, wfT, Wm_w, qt_bf);
  k_attn<<<BB * EE, 512, 0, stream>>>(keys, qt_bf, masks, out);
}

// Round 15
// 145.845 us; speedup vs baseline: 1.0598x; 1.0598x over previous
//
#include <hip/hip_runtime.h>
#include <hip/hip_bf16.h>

#define BB 16
#define EE 128
#define MM 64
#define DQ 768
#define DK 256
#define NT 8   // tiles (consecutive a, same b) per block; grid 256 = 1 block/CU

typedef __attribute__((ext_vector_type(8))) short short8v;    // 8 bf16 = 4 VGPR
typedef __attribute__((ext_vector_type(4))) float f32x4;
typedef __attribute__((ext_vector_type(16))) float f32x16;

#define MFMA16(a, b, c) __builtin_amdgcn_mfma_f32_16x16x32_bf16(a, b, c, 0, 0, 0)
#define MFMA32(a, b, c) __builtin_amdgcn_mfma_f32_32x32x16_bf16(a, b, c, 0, 0, 0)

// LDS-only barrier: leaves global loads/stores (and the DMA) in flight
#define LDS_BARRIER() asm volatile("s_waitcnt lgkmcnt(0)\n\ts_barrier" ::: "memory")
// full drain: DMA landed + stores retired; once per tile
#define DRAIN_BARRIER() \
  asm volatile("s_waitcnt vmcnt(0) lgkmcnt(0)\n\ts_barrier" ::: "memory")

typedef const __attribute__((address_space(1))) unsigned int gq_t;
typedef __attribute__((address_space(3))) unsigned int lq_t;

__device__ __forceinline__ ushort f2bf(float f) {
  __hip_bfloat16 h = __float2bfloat16(f);
  return *reinterpret_cast<ushort*>(&h);
}
__device__ __forceinline__ uint pack2(float lo, float hi) {
  return (uint)f2bf(lo) | ((uint)f2bf(hi) << 16);
}

// ---------------------------------------------------------------------------
// K1: WfT[e][d] = sum_k Wq[d][k] * Wk[e][k]  (= (Wq @ Wk^T)^T, bf16) via MFMA.
// ---------------------------------------------------------------------------
__global__ __launch_bounds__(64) void k_wfuse(const float* __restrict__ Wq,
                                              const float* __restrict__ Wk,
                                              ushort* __restrict__ wfT) {
  const int lane = threadIdx.x & 63;
  const int lo = lane & 15, hi = lane >> 4;
  const int e0 = blockIdx.x * 16;
  const int d0 = blockIdx.y * 64;
  f32x4 acc[4] = {f32x4{0.f, 0.f, 0.f, 0.f}, f32x4{0.f, 0.f, 0.f, 0.f},
                  f32x4{0.f, 0.f, 0.f, 0.f}, f32x4{0.f, 0.f, 0.f, 0.f}};
#pragma unroll
  for (int ks = 0; ks < 8; ++ks) {
    const int k = ks * 32 + 8 * hi;
    const float4 a0 = *(const float4*)&Wk[(size_t)(e0 + lo) * DK + k];
    const float4 a1 = *(const float4*)&Wk[(size_t)(e0 + lo) * DK + k + 4];
    union { short8v v; uint u[4]; } av;
    av.u[0] = pack2(a0.x, a0.y); av.u[1] = pack2(a0.z, a0.w);
    av.u[2] = pack2(a1.x, a1.y); av.u[3] = pack2(a1.z, a1.w);
#pragma unroll
    for (int dt = 0; dt < 4; ++dt) {
      const float4 b0 = *(const float4*)&Wq[(size_t)(d0 + dt * 16 + lo) * DK + k];
      const float4 b1 = *(const float4*)&Wq[(size_t)(d0 + dt * 16 + lo) * DK + k + 4];
      union { short8v v; uint u[4]; } bv;
      bv.u[0] = pack2(b0.x, b0.y); bv.u[1] = pack2(b0.z, b0.w);
      bv.u[2] = pack2(b1.x, b1.y); bv.u[3] = pack2(b1.z, b1.w);
      acc[dt] = MFMA16(av.v, bv.v, acc[dt]);
    }
  }
#pragma unroll
  for (int dt = 0; dt < 4; ++dt)
#pragma unroll
    for (int r = 0; r < 4; ++r)
      wfT[(size_t)(e0 + 4 * hi + r) * DQ + d0 + dt * 16 + lo] = f2bf(acc[dt][r]);
}

// ---------------------------------------------------------------------------
// K2: qt2[r][e] = (sum_d relu(querys[r][d]) * WfT[e][d]) * scale + Wm_w[e].
// ---------------------------------------------------------------------------
__global__ __launch_bounds__(128) void k_qt(const float* __restrict__ querys,
                                            const ushort* __restrict__ wfT,
                                            const float* __restrict__ wm_w,
                                            ushort* __restrict__ qt) {
  const int tid = threadIdx.x;
  const int w = tid >> 6;
  const int lane = tid & 63;
  const int lo = lane & 15, hi = lane >> 4;
  const int r0 = blockIdx.x * 32 + w * 16;
  const int e0 = blockIdx.y * 64;
  const float* qrow = querys + (size_t)(r0 + lo) * DQ;
  f32x4 acc[4] = {f32x4{0.f, 0.f, 0.f, 0.f}, f32x4{0.f, 0.f, 0.f, 0.f},
                  f32x4{0.f, 0.f, 0.f, 0.f}, f32x4{0.f, 0.f, 0.f, 0.f}};
#pragma unroll
  for (int kc = 0; kc < DQ; kc += 32) {
    const int k = kc + 8 * hi;
    const float4 a0 = *(const float4*)&qrow[k];
    const float4 a1 = *(const float4*)&qrow[k + 4];
    union { short8v v; uint u[4]; } af;
    af.u[0] = pack2(fmaxf(a0.x, 0.f), fmaxf(a0.y, 0.f));
    af.u[1] = pack2(fmaxf(a0.z, 0.f), fmaxf(a0.w, 0.f));
    af.u[2] = pack2(fmaxf(a1.x, 0.f), fmaxf(a1.y, 0.f));
    af.u[3] = pack2(fmaxf(a1.z, 0.f), fmaxf(a1.w, 0.f));
#pragma unroll
    for (int et = 0; et < 4; ++et) {
      const short8v bf = *(const short8v*)&wfT[(size_t)(e0 + et * 16 + lo) * DQ + k];
      acc[et] = MFMA16(af.v, bf, acc[et]);
    }
  }
  const float sc = 0.036084391824351615f;  // 1/sqrt(768)
#pragma unroll
  for (int et = 0; et < 4; ++et) {
    const float wmv = wm_w[e0 + et * 16 + lo];
#pragma unroll
    for (int r = 0; r < 4; ++r)
      qt[(size_t)(r0 + hi * 4 + r) * DK + e0 + et * 16 + lo] =
          f2bf(fmaf(acc[et][r], sc, wmv));
  }
}

// ---------------------------------------------------------------------------
// K3: fused MFMA attention, NT=8 DMA-pipelined. 512 thr = 8 waves, grid 256
// (1 block/CU). r11's verified compute blocks verbatim; staging replaced by
// global_load_lds width=16 async DMA into a 64K f32 landing buffer X:
//   per tile i: convert X->relu,kT (LDS->LDS, wave-local slices) | BAR |
//               issue DMA tile i+1 -> X (0 VGPRs, lands under compute) |
//               QK(swapped 16x16) -> softmax(+mask) -> P->P_lds | BAR |
//               PV 32x32 C[q][d] full-line stores | vmcnt(0) DRAIN BAR.
// LDS: X 64K + relu 32K (swz (m&7)<<4) + kT 32K (swz ((d&7)^((d>>3)&7))<<4)
//      + P 16K = 144 KiB (r14 bug: relu was declared 16K and overflowed into
//      kT — fixed). (512,2) -> 256-VGPR cap: spill excluded.
// ---------------------------------------------------------------------------
__global__ __launch_bounds__(512, 2) void k_attn(
    const float* __restrict__ keys, const ushort* __restrict__ qt,
    const int* __restrict__ masks, float* __restrict__ out) {
  __shared__ float Xs[MM * DK];          // 64 KiB DMA landing (linear f32)
  __shared__ ushort relu_lds[MM * DK];   // 32 KiB (bf16 64x256)  [FIXED SIZE]
  __shared__ ushort kT_lds[DK * MM];     // 32 KiB (bf16 256x64)
  __shared__ ushort P_lds[EE * MM];      // 16 KiB

  const int tid = threadIdx.x;
  const int w = tid >> 6;
  const int lane = tid & 63;
  const int lo = lane & 15, hi = lane >> 4;
  const int ba0 = blockIdx.x * NT;
  const int b = ba0 >> 7;                // NT | 128 -> b fixed

  // qt2 B-fragments (cols q = w*16+lo): loaded once, persistent (256 cap)
  const ushort* qrowp = qt + ((size_t)b * EE + w * 16 + lo) * DK + 8 * hi;
  short8v aq[8];
#pragma unroll
  for (int ks = 0; ks < 8; ++ks) aq[ks] = *(const short8v*)(qrowp + 32 * ks);

  // ---- DMA: wave w copies its 8 KiB slice (rows w*8..w*8+7) of tile t ----
  auto dma = [&](int t) {
    const char* g = (const char*)(keys + (size_t)(ba0 + t) * (MM * DK)) +
                    w * 8192 + lane * 16;
    char* l = (char*)Xs + w * 8192;      // wave-uniform LDS base
#pragma unroll
    for (int k = 0; k < 8; ++k)
      __builtin_amdgcn_global_load_lds((gq_t*)(g + k * 1024),
                                       (lq_t*)(l + k * 1024), 16, 0, 0);
  };

  // ---- convert: X (f32, rows w*8..w*8+7 for this wave) -> relu + kT bf16 --
  auto convert = [&]() {
    const int m0 = w * 8 + hi * 2;
    const float4* xb = (const float4*)Xs;
#pragma unroll
    for (int it = 0; it < 4; ++it) {
      const int c = lo + 16 * it;
      const float4 va = xb[(size_t)m0 * 64 + c];
      const float4 vb = xb[(size_t)(m0 + 1) * 64 + c];
      uint2 ra, rb;
      ra.x = pack2(fmaxf(va.x, 0.f), fmaxf(va.y, 0.f));
      ra.y = pack2(fmaxf(va.z, 0.f), fmaxf(va.w, 0.f));
      rb.x = pack2(fmaxf(vb.x, 0.f), fmaxf(vb.y, 0.f));
      rb.y = pack2(fmaxf(vb.z, 0.f), fmaxf(vb.w, 0.f));
      *(uint2*)((char*)relu_lds + (size_t)m0 * 512 +
                ((8 * c) ^ ((m0 & 7) << 4))) = ra;
      *(uint2*)((char*)relu_lds + (size_t)(m0 + 1) * 512 +
                ((8 * c) ^ (((m0 + 1) & 7) << 4))) = rb;
      const float va4[4] = {va.x, va.y, va.z, va.w};
      const float vb4[4] = {vb.x, vb.y, vb.z, vb.w};
#pragma unroll
      for (int j = 0; j < 4; ++j) {
        const int d = 4 * c + j;
        const int sw = ((d & 7) ^ ((d >> 3) & 7)) << 4;
        *(uint*)((char*)kT_lds + (size_t)d * 128 + ((2 * m0) ^ sw)) =
            pack2(va4[j], vb4[j]);
      }
    }
  };

  // ---- prologue ----
  dma(0);
  DRAIN_BARRIER();           // X[0] landed on all waves

  for (int i = 0; i < NT; ++i) {
    const int ba = ba0 + i;

    convert();               // X -> relu,kT (wave-local X slice)
    LDS_BARRIER();           // relu/kT visible; X consumed
    if (i + 1 < NT) dma(i + 1);   // async; lands under QK/softmax/PV

    // mask bits for this lane's softmax rows: m = mt*16 + hi*4 .. +3
    const int4* mrow = (const int4*)(masks + (size_t)ba * MM);
    int4 mk4[4];
#pragma unroll
    for (int mt = 0; mt < 4; ++mt) mk4[mt] = mrow[mt * 4 + hi];

    // ====== QK^T swapped 16x16: full logits S^T[m][q], lane q = w*16+lo ====
    f32x4 sacc[4] = {f32x4{0.f, 0.f, 0.f, 0.f}, f32x4{0.f, 0.f, 0.f, 0.f},
                     f32x4{0.f, 0.f, 0.f, 0.f}, f32x4{0.f, 0.f, 0.f, 0.f}};
    __builtin_amdgcn_s_setprio(1);
#pragma unroll
    for (int ks = 0; ks < 8; ++ks) {
#pragma unroll
      for (int mt = 0; mt < 4; ++mt) {
        const int m = mt * 16 + lo;
        const int k = ks * 32 + 8 * hi;
        const short8v bf = *(const short8v*)((char*)relu_lds +
                                             (size_t)m * 512 +
                                             ((2 * k) ^ ((m & 7) << 4)));
        sacc[mt] = MFMA16(bf, aq[ks], sacc[mt]);  // A = relu_k, B = qt2
      }
    }
    __builtin_amdgcn_s_setprio(0);

    // ============ softmax: mask select, in-lane 16 m + shfl_xor 16,32 ======
    float l[4][4];
    float mx = -3.4e38f;
#pragma unroll
    for (int mt = 0; mt < 4; ++mt) {
      const int mkb[4] = {mk4[mt].x, mk4[mt].y, mk4[mt].z, mk4[mt].w};
#pragma unroll
      for (int r = 0; r < 4; ++r) {
        l[mt][r] = (mkb[r] != 0) ? sacc[mt][r] : -1e30f;
        mx = fmaxf(mx, l[mt][r]);
      }
    }
    mx = fmaxf(mx, __shfl_xor(mx, 16));
    mx = fmaxf(mx, __shfl_xor(mx, 32));
    float s = 0.f;
#pragma unroll
    for (int mt = 0; mt < 4; ++mt)
#pragma unroll
      for (int r = 0; r < 4; ++r) {
        l[mt][r] = __expf(l[mt][r] - mx);
        s += l[mt][r];
      }
    s += __shfl_xor(s, 16);
    s += __shfl_xor(s, 32);
    const float rinv = 1.f / s;

    // ================= P -> P_lds (bf16, swizzled rows of 128B) ============
    {
      const int q = w * 16 + lo;
      const int swq = ((q & 7) ^ ((q >> 3) & 7)) << 4;
#pragma unroll
      for (int mt = 0; mt < 4; ++mt) {
        uint2 pv;
        pv.x = pack2(l[mt][0] * rinv, l[mt][1] * rinv);
        pv.y = pack2(l[mt][2] * rinv, l[mt][3] * rinv);
        *(uint2*)((char*)P_lds + (size_t)q * 128 +
                  ((32 * mt + 8 * hi) ^ swq)) = pv;
      }
    }
    LDS_BARRIER();   // P complete (prev PV reads covered by prior DRAIN)

    // ================= PV: NON-swapped 32x32x16, C[q][d] ===================
    // Every per-reg store = 32 lanes x 4B consecutive d = full 128B line.
    {
      const int l31 = lane & 31, lh = lane >> 5;
      const int qb = (w & 3) * 32;
      const int db = (w >> 2) * 128;
      const int qa = qb + l31;
      const int swqa = ((qa & 7) ^ ((qa >> 3) & 7)) << 4;
      short8v pa[4];
#pragma unroll
      for (int ms = 0; ms < 4; ++ms)
        pa[ms] = *(const short8v*)((char*)P_lds + (size_t)qa * 128 +
                                   ((32 * ms + 16 * lh) ^ swqa));
      float* ob = out + (size_t)ba * EE * DK;
      __builtin_amdgcn_s_setprio(1);
#pragma unroll
      for (int t = 0; t < 4; ++t) {
        const int d = db + t * 32 + l31;
        const int swd = ((d & 7) ^ ((d >> 3) & 7)) << 4;
        f32x16 o = 0.f;
#pragma unroll
        for (int ms = 0; ms < 4; ++ms) {
          const short8v bk = *(const short8v*)((char*)kT_lds +
                                               (size_t)d * 128 +
                                               ((32 * ms + 16 * lh) ^ swd));
          o = MFMA32(pa[ms], bk, o);
        }
#pragma unroll
        for (int r = 0; r < 16; ++r) {
          const int qrow = qb + (r & 3) + 8 * (r >> 2) + 4 * lh;
          ob[(size_t)qrow * DK + d] = o[r];
        }
      }
      __builtin_amdgcn_s_setprio(0);
    }

    if (i + 1 < NT) DRAIN_BARRIER();  // DMA landed; relu/kT/P safe to reuse
  }
}

// ---------------------------------------------------------------------------
extern "C" void kernel_launch(void* const* d_in, const int* in_sizes, int n_in,
                              void* d_out, int out_size, void* d_ws, size_t ws_size,
                              hipStream_t stream) {
  const float* querys = (const float*)d_in[0];  // [16,128,768]
  const float* keys   = (const float*)d_in[1];  // [16,128,64,256]
  const float* Wq     = (const float*)d_in[2];  // [768,256]
  const float* Wk     = (const float*)d_in[3];  // [256,256]
  const float* Wm_w   = (const float*)d_in[4];  // [256]
  // d_in[5] = Wm_b: row-constant logit shift -> cancels in softmax; unused.
  const int*   masks  = (const int*)d_in[6];    // [16,128,64]
  float* out = (float*)d_out;                   // [16,128,128,256]

  ushort* wfT   = (ushort*)d_ws;                          // 256*768 bf16
  ushort* qt_bf = (ushort*)((char*)d_ws + DK * DQ * 2);   // 2048*256 bf16

  k_wfuse<<<dim3(DK / 16, DQ / 64), 64, 0, stream>>>(Wq, Wk, wfT);
  k_qt<<<dim3((BB * EE) / 32, DK / 64), 128, 0, stream>>>(querys, wfT, Wm_w, qt_bf);
  k_attn<<<(BB * EE) / NT, 512, 0, stream>>>(keys, qt_bf, masks, out);
}

// Round 16
// 112.243 us; speedup vs baseline: 1.3771x; 1.2994x over previous
//
#include <hip/hip_runtime.h>
#include <hip/hip_bf16.h>

#define BB 16
#define EE 128
#define MM 64
#define DQ 768
#define DK 256
#define NT 8   // tiles (consecutive a, same b) per block; grid 256 = 1 block/CU

typedef __attribute__((ext_vector_type(8))) short short8v;    // 8 bf16 = 4 VGPR
typedef __attribute__((ext_vector_type(4))) float f32x4;
typedef __attribute__((ext_vector_type(16))) float f32x16;

#define MFMA16(a, b, c) __builtin_amdgcn_mfma_f32_16x16x32_bf16(a, b, c, 0, 0, 0)
#define MFMA32(a, b, c) __builtin_amdgcn_mfma_f32_32x32x16_bf16(a, b, c, 0, 0, 0)

// LDS-only barrier: leaves global loads/stores (and the DMA) in flight
#define LDS_BARRIER() asm volatile("s_waitcnt lgkmcnt(0)\n\ts_barrier" ::: "memory")
// full drain (prologue only)
#define DRAIN_BARRIER() \
  asm volatile("s_waitcnt vmcnt(0) lgkmcnt(0)\n\ts_barrier" ::: "memory")
// counted drain (T4): guarantees the 8 DMA loads (issued before this tile's
// 64 stores + 1 mask load) have landed, while leaving up to 63 output
// stores in flight across the barrier. Never vmcnt(0) in the main loop.
#define TILE_BARRIER() \
  asm volatile("s_waitcnt vmcnt(63) lgkmcnt(0)\n\ts_barrier" ::: "memory")

typedef const __attribute__((address_space(1))) unsigned int gq_t;
typedef __attribute__((address_space(3))) unsigned int lq_t;

__device__ __forceinline__ ushort f2bf(float f) {
  __hip_bfloat16 h = __float2bfloat16(f);
  return *reinterpret_cast<ushort*>(&h);
}
__device__ __forceinline__ uint pack2(float lo, float hi) {
  return (uint)f2bf(lo) | ((uint)f2bf(hi) << 16);
}

// ---------------------------------------------------------------------------
// K1: WfT[e][d] = sum_k Wq[d][k] * Wk[e][k]  (= (Wq @ Wk^T)^T, bf16) via MFMA.
// ---------------------------------------------------------------------------
__global__ __launch_bounds__(64) void k_wfuse(const float* __restrict__ Wq,
                                              const float* __restrict__ Wk,
                                              ushort* __restrict__ wfT) {
  const int lane = threadIdx.x & 63;
  const int lo = lane & 15, hi = lane >> 4;
  const int e0 = blockIdx.x * 16;
  const int d0 = blockIdx.y * 64;
  f32x4 acc[4] = {f32x4{0.f, 0.f, 0.f, 0.f}, f32x4{0.f, 0.f, 0.f, 0.f},
                  f32x4{0.f, 0.f, 0.f, 0.f}, f32x4{0.f, 0.f, 0.f, 0.f}};
#pragma unroll
  for (int ks = 0; ks < 8; ++ks) {
    const int k = ks * 32 + 8 * hi;
    const float4 a0 = *(const float4*)&Wk[(size_t)(e0 + lo) * DK + k];
    const float4 a1 = *(const float4*)&Wk[(size_t)(e0 + lo) * DK + k + 4];
    union { short8v v; uint u[4]; } av;
    av.u[0] = pack2(a0.x, a0.y); av.u[1] = pack2(a0.z, a0.w);
    av.u[2] = pack2(a1.x, a1.y); av.u[3] = pack2(a1.z, a1.w);
#pragma unroll
    for (int dt = 0; dt < 4; ++dt) {
      const float4 b0 = *(const float4*)&Wq[(size_t)(d0 + dt * 16 + lo) * DK + k];
      const float4 b1 = *(const float4*)&Wq[(size_t)(d0 + dt * 16 + lo) * DK + k + 4];
      union { short8v v; uint u[4]; } bv;
      bv.u[0] = pack2(b0.x, b0.y); bv.u[1] = pack2(b0.z, b0.w);
      bv.u[2] = pack2(b1.x, b1.y); bv.u[3] = pack2(b1.z, b1.w);
      acc[dt] = MFMA16(av.v, bv.v, acc[dt]);
    }
  }
#pragma unroll
  for (int dt = 0; dt < 4; ++dt)
#pragma unroll
    for (int r = 0; r < 4; ++r)
      wfT[(size_t)(e0 + 4 * hi + r) * DQ + d0 + dt * 16 + lo] = f2bf(acc[dt][r]);
}

// ---------------------------------------------------------------------------
// K2: qt2[r][e] = (sum_d relu(querys[r][d]) * WfT[e][d]) * scale + Wm_w[e].
// ---------------------------------------------------------------------------
__global__ __launch_bounds__(128) void k_qt(const float* __restrict__ querys,
                                            const ushort* __restrict__ wfT,
                                            const float* __restrict__ wm_w,
                                            ushort* __restrict__ qt) {
  const int tid = threadIdx.x;
  const int w = tid >> 6;
  const int lane = tid & 63;
  const int lo = lane & 15, hi = lane >> 4;
  const int r0 = blockIdx.x * 32 + w * 16;
  const int e0 = blockIdx.y * 64;
  const float* qrow = querys + (size_t)(r0 + lo) * DQ;
  f32x4 acc[4] = {f32x4{0.f, 0.f, 0.f, 0.f}, f32x4{0.f, 0.f, 0.f, 0.f},
                  f32x4{0.f, 0.f, 0.f, 0.f}, f32x4{0.f, 0.f, 0.f, 0.f}};
#pragma unroll
  for (int kc = 0; kc < DQ; kc += 32) {
    const int k = kc + 8 * hi;
    const float4 a0 = *(const float4*)&qrow[k];
    const float4 a1 = *(const float4*)&qrow[k + 4];
    union { short8v v; uint u[4]; } af;
    af.u[0] = pack2(fmaxf(a0.x, 0.f), fmaxf(a0.y, 0.f));
    af.u[1] = pack2(fmaxf(a0.z, 0.f), fmaxf(a0.w, 0.f));
    af.u[2] = pack2(fmaxf(a1.x, 0.f), fmaxf(a1.y, 0.f));
    af.u[3] = pack2(fmaxf(a1.z, 0.f), fmaxf(a1.w, 0.f));
#pragma unroll
    for (int et = 0; et < 4; ++et) {
      const short8v bf = *(const short8v*)&wfT[(size_t)(e0 + et * 16 + lo) * DQ + k];
      acc[et] = MFMA16(af.v, bf, acc[et]);
    }
  }
  const float sc = 0.036084391824351615f;  // 1/sqrt(768)
#pragma unroll
  for (int et = 0; et < 4; ++et) {
    const float wmv = wm_w[e0 + et * 16 + lo];
#pragma unroll
    for (int r = 0; r < 4; ++r)
      qt[(size_t)(r0 + hi * 4 + r) * DK + e0 + et * 16 + lo] =
          f2bf(fmaf(acc[et][r], sc, wmv));
  }
}

// ---------------------------------------------------------------------------
// K3: fused MFMA attention, NT=8 DMA-pipelined, counted-vmcnt edition.
// 512 thr = 8 waves, grid 256 (1 block/CU). Per tile i:
//   convert X->relu,kT (LDS->LDS, wave-local) | LDS BAR |
//   issue DMA tile i+1 -> X | QK(swapped 16x16) -> softmax(+mask) -> P |
//   LDS BAR | PV 32x32 C[q][d], NONTEMPORAL full-line stores |
//   TILE BAR: vmcnt(63) — DMAs landed, stores stay in flight (T4).
// LDS: X 64K + relu 32K + kT 32K + P 16K = 144 KiB. (512,2): no spill.
// ---------------------------------------------------------------------------
__global__ __launch_bounds__(512, 2) void k_attn(
    const float* __restrict__ keys, const ushort* __restrict__ qt,
    const int* __restrict__ masks, float* __restrict__ out) {
  __shared__ float Xs[MM * DK];          // 64 KiB DMA landing (linear f32)
  __shared__ ushort relu_lds[MM * DK];   // 32 KiB (bf16 64x256)
  __shared__ ushort kT_lds[DK * MM];     // 32 KiB (bf16 256x64)
  __shared__ ushort P_lds[EE * MM];      // 16 KiB

  const int tid = threadIdx.x;
  const int w = tid >> 6;
  const int lane = tid & 63;
  const int lo = lane & 15, hi = lane >> 4;
  const int ba0 = blockIdx.x * NT;
  const int b = ba0 >> 7;                // NT | 128 -> b fixed

  // qt2 B-fragments (cols q = w*16+lo): loaded once, persistent (256 cap)
  const ushort* qrowp = qt + ((size_t)b * EE + w * 16 + lo) * DK + 8 * hi;
  short8v aq[8];
#pragma unroll
  for (int ks = 0; ks < 8; ++ks) aq[ks] = *(const short8v*)(qrowp + 32 * ks);

  // ---- DMA: wave w copies its 8 KiB slice (rows w*8..w*8+7) of tile t ----
  auto dma = [&](int t) {
    const char* g = (const char*)(keys + (size_t)(ba0 + t) * (MM * DK)) +
                    w * 8192 + lane * 16;
    char* l = (char*)Xs + w * 8192;      // wave-uniform LDS base
#pragma unroll
    for (int k = 0; k < 8; ++k)
      __builtin_amdgcn_global_load_lds((gq_t*)(g + k * 1024),
                                       (lq_t*)(l + k * 1024), 16, 0, 0);
  };

  // ---- convert: X (f32, rows w*8..w*8+7 for this wave) -> relu + kT bf16 --
  auto convert = [&]() {
    const int m0 = w * 8 + hi * 2;
    const float4* xb = (const float4*)Xs;
#pragma unroll
    for (int it = 0; it < 4; ++it) {
      const int c = lo + 16 * it;
      const float4 va = xb[(size_t)m0 * 64 + c];
      const float4 vb = xb[(size_t)(m0 + 1) * 64 + c];
      uint2 ra, rb;
      ra.x = pack2(fmaxf(va.x, 0.f), fmaxf(va.y, 0.f));
      ra.y = pack2(fmaxf(va.z, 0.f), fmaxf(va.w, 0.f));
      rb.x = pack2(fmaxf(vb.x, 0.f), fmaxf(vb.y, 0.f));
      rb.y = pack2(fmaxf(vb.z, 0.f), fmaxf(vb.w, 0.f));
      *(uint2*)((char*)relu_lds + (size_t)m0 * 512 +
                ((8 * c) ^ ((m0 & 7) << 4))) = ra;
      *(uint2*)((char*)relu_lds + (size_t)(m0 + 1) * 512 +
                ((8 * c) ^ (((m0 + 1) & 7) << 4))) = rb;
      const float va4[4] = {va.x, va.y, va.z, va.w};
      const float vb4[4] = {vb.x, vb.y, vb.z, vb.w};
#pragma unroll
      for (int j = 0; j < 4; ++j) {
        const int d = 4 * c + j;
        const int sw = ((d & 7) ^ ((d >> 3) & 7)) << 4;
        *(uint*)((char*)kT_lds + (size_t)d * 128 + ((2 * m0) ^ sw)) =
            pack2(va4[j], vb4[j]);
      }
    }
  };

  // ---- prologue ----
  dma(0);
  DRAIN_BARRIER();           // X[0] landed on all waves (vmcnt(0) OK here)

  for (int i = 0; i < NT; ++i) {
    const int ba = ba0 + i;

    convert();               // X -> relu,kT (wave-local X slice)
    LDS_BARRIER();           // relu/kT visible; X consumed
    if (i + 1 < NT) dma(i + 1);   // async; lands under QK/softmax/PV

    // mask bits for this lane's softmax rows: m = mt*16 + hi*4 .. +3
    const int4* mrow = (const int4*)(masks + (size_t)ba * MM);
    int4 mk4[4];
#pragma unroll
    for (int mt = 0; mt < 4; ++mt) mk4[mt] = mrow[mt * 4 + hi];

    // ====== QK^T swapped 16x16: full logits S^T[m][q], lane q = w*16+lo ====
    f32x4 sacc[4] = {f32x4{0.f, 0.f, 0.f, 0.f}, f32x4{0.f, 0.f, 0.f, 0.f},
                     f32x4{0.f, 0.f, 0.f, 0.f}, f32x4{0.f, 0.f, 0.f, 0.f}};
    __builtin_amdgcn_s_setprio(1);
#pragma unroll
    for (int ks = 0; ks < 8; ++ks) {
#pragma unroll
      for (int mt = 0; mt < 4; ++mt) {
        const int m = mt * 16 + lo;
        const int k = ks * 32 + 8 * hi;
        const short8v bf = *(const short8v*)((char*)relu_lds +
                                             (size_t)m * 512 +
                                             ((2 * k) ^ ((m & 7) << 4)));
        sacc[mt] = MFMA16(bf, aq[ks], sacc[mt]);  // A = relu_k, B = qt2
      }
    }
    __builtin_amdgcn_s_setprio(0);

    // ============ softmax: mask select, in-lane 16 m + shfl_xor 16,32 ======
    float l[4][4];
    float mx = -3.4e38f;
#pragma unroll
    for (int mt = 0; mt < 4; ++mt) {
      const int mkb[4] = {mk4[mt].x, mk4[mt].y, mk4[mt].z, mk4[mt].w};
#pragma unroll
      for (int r = 0; r < 4; ++r) {
        l[mt][r] = (mkb[r] != 0) ? sacc[mt][r] : -1e30f;
        mx = fmaxf(mx, l[mt][r]);
      }
    }
    mx = fmaxf(mx, __shfl_xor(mx, 16));
    mx = fmaxf(mx, __shfl_xor(mx, 32));
    float s = 0.f;
#pragma unroll
    for (int mt = 0; mt < 4; ++mt)
#pragma unroll
      for (int r = 0; r < 4; ++r) {
        l[mt][r] = __expf(l[mt][r] - mx);
        s += l[mt][r];
      }
    s += __shfl_xor(s, 16);
    s += __shfl_xor(s, 32);
    const float rinv = 1.f / s;

    // ================= P -> P_lds (bf16, swizzled rows of 128B) ============
    {
      const int q = w * 16 + lo;
      const int swq = ((q & 7) ^ ((q >> 3) & 7)) << 4;
#pragma unroll
      for (int mt = 0; mt < 4; ++mt) {
        uint2 pv;
        pv.x = pack2(l[mt][0] * rinv, l[mt][1] * rinv);
        pv.y = pack2(l[mt][2] * rinv, l[mt][3] * rinv);
        *(uint2*)((char*)P_lds + (size_t)q * 128 +
                  ((32 * mt + 8 * hi) ^ swq)) = pv;
      }
    }
    LDS_BARRIER();   // P complete

    // ================= PV: NON-swapped 32x32x16, C[q][d] ===================
    // Nontemporal stores: out is write-once — keep it out of L2.
    {
      const int l31 = lane & 31, lh = lane >> 5;
      const int qb = (w & 3) * 32;
      const int db = (w >> 2) * 128;
      const int qa = qb + l31;
      const int swqa = ((qa & 7) ^ ((qa >> 3) & 7)) << 4;
      short8v pa[4];
#pragma unroll
      for (int ms = 0; ms < 4; ++ms)
        pa[ms] = *(const short8v*)((char*)P_lds + (size_t)qa * 128 +
                                   ((32 * ms + 16 * lh) ^ swqa));
      float* ob = out + (size_t)ba * EE * DK;
      __builtin_amdgcn_s_setprio(1);
#pragma unroll
      for (int t = 0; t < 4; ++t) {
        const int d = db + t * 32 + l31;
        const int swd = ((d & 7) ^ ((d >> 3) & 7)) << 4;
        f32x16 o = 0.f;
#pragma unroll
        for (int ms = 0; ms < 4; ++ms) {
          const short8v bk = *(const short8v*)((char*)kT_lds +
                                               (size_t)d * 128 +
                                               ((32 * ms + 16 * lh) ^ swd));
          o = MFMA32(pa[ms], bk, o);
        }
#pragma unroll
        for (int r = 0; r < 16; ++r) {
          const int qrow = qb + (r & 3) + 8 * (r >> 2) + 4 * lh;
          __builtin_nontemporal_store(o[r], &ob[(size_t)qrow * DK + d]);
        }
      }
      __builtin_amdgcn_s_setprio(0);
    }

    if (i + 1 < NT) TILE_BARRIER();  // vmcnt(63): DMAs landed, stores in flight
  }
}

// ---------------------------------------------------------------------------
extern "C" void kernel_launch(void* const* d_in, const int* in_sizes, int n_in,
                              void* d_out, int out_size, void* d_ws, size_t ws_size,
                              hipStream_t stream) {
  const float* querys = (const float*)d_in[0];  // [16,128,768]
  const float* keys   = (const float*)d_in[1];  // [16,128,64,256]
  const float* Wq     = (const float*)d_in[2];  // [768,256]
  const float* Wk     = (const float*)d_in[3];  // [256,256]
  const float* Wm_w   = (const float*)d_in[4];  // [256]
  // d_in[5] = Wm_b: row-constant logit shift -> cancels in softmax; unused.
  const int*   masks  = (const int*)d_in[6];    // [16,128,64]
  float* out = (float*)d_out;                   // [16,128,128,256]

  ushort* wfT   = (ushort*)d_ws;                          // 256*768 bf16
  ushort* qt_bf = (ushort*)((char*)d_ws + DK * DQ * 2);   // 2048*256 bf16

  k_wfuse<<<dim3(DK / 16, DQ / 64), 64, 0, stream>>>(Wq, Wk, wfT);
  k_qt<<<dim3((BB * EE) / 32, DK / 64), 128, 0, stream>>>(querys, wfT, Wm_w, qt_bf);
  k_attn<<<(BB * EE) / NT, 512, 0, stream>>>(keys, qt_bf, masks, out);
}